// Round 3
// baseline (461.526 us; speedup 1.0000x reference)
//
#include <hip/hip_runtime.h>

// Problem constants (fixed by reference: B=4, C=512, H=W=64, MID=64)
#define BB 4
#define CD 512
#define NP 4096
#define MID 64
#define PSTR 68   // pbuf/obuf row stride (68 dwords/halves -> ~2-way banks, free)

typedef _Float16 half8 __attribute__((ext_vector_type(8)));
typedef _Float16 half4 __attribute__((ext_vector_type(4)));
typedef float floatx4 __attribute__((ext_vector_type(4)));

#define LOG2E 1.4426950408889634f

// ---------------------------------------------------------------------------
// Kernel 1: pack wq|wk|wv -> fp16 [640][512], concat biases (fp32 [640]).
// log2(e) folded into wq/bq so softmax uses raw v_exp_f32 (exp2).
// ---------------------------------------------------------------------------
__global__ __launch_bounds__(256) void prep_w(
    const float* __restrict__ wq, const float* __restrict__ wk,
    const float* __restrict__ wv, const float* __restrict__ bq,
    const float* __restrict__ bk, const float* __restrict__ bv,
    _Float16* __restrict__ w_h, float* __restrict__ bias) {
  int idx = blockIdx.x * 256 + threadIdx.x;
  for (int i = idx; i < 640 * 512; i += gridDim.x * 256) {
    int r = i >> 9, c = i & 511;
    float v = (r < 64) ? wq[(r << 9) + c] * LOG2E
            : (r < 128) ? wk[((r - 64) << 9) + c]
                        : wv[((r - 128) << 9) + c];
    w_h[i] = (_Float16)v;
  }
  if (idx < 640) {
    float v = (idx < 64) ? bq[idx] * LOG2E
            : (idx < 128) ? bk[idx - 64]
                          : bv[idx - 128];
    bias[idx] = v;
  }
}

// ---------------------------------------------------------------------------
// Kernel 2: transpose x [b][c][n] fp32 -> xt [b][n][c] fp16 (64x64 LDS tiles)
// ---------------------------------------------------------------------------
__global__ __launch_bounds__(256) void transpose_x(const float* __restrict__ x,
                                                   _Float16* __restrict__ xt) {
  __shared__ float tile[64][65];
  int b = blockIdx.z, c0 = blockIdx.y * 64, n0 = blockIdx.x * 64;
  int t = threadIdx.x;
  const float* xb = x + (size_t)b * CD * NP;
#pragma unroll
  for (int k = 0; k < 16; k++) {
    int cl = k * 4 + (t >> 6);
    int nl = t & 63;
    tile[cl][nl] = xb[(size_t)(c0 + cl) * NP + n0 + nl];
  }
  __syncthreads();
  _Float16* xtb = xt + ((size_t)b * NP + n0) * CD + c0;
#pragma unroll
  for (int k = 0; k < 2; k++) {
    int nl = k * 32 + (t >> 3);
    int cl = (t & 7) * 8;
    half8 pk;
#pragma unroll
    for (int i = 0; i < 8; i++) pk[i] = (_Float16)tile[cl + i][nl];
    *(half8*)(xtb + (size_t)nl * CD + cl) = pk;
  }
}

// ---------------------------------------------------------------------------
// Kernel 3: fused QKV projection. One wave per block, 64 rows x 64 cols tile.
// ---------------------------------------------------------------------------
__global__ __launch_bounds__(64) void proj_qkv(
    const _Float16* __restrict__ w_h, const float* __restrict__ bias,
    const _Float16* __restrict__ xt, _Float16* __restrict__ q_h,
    _Float16* __restrict__ k_h, _Float16* __restrict__ v_h) {
  __shared__ _Float16 st[64 * 72];
  int lane = threadIdx.x;
  int col = lane & 15, quad = lane >> 4;
  int rb = blockIdx.x;          // 0..9  (64 W-rows each)
  int nb = blockIdx.y;          // 0..63 (64 positions each)
  int b = blockIdx.z;
  int r0 = rb * 64, n0 = nb * 64;
  const _Float16* xtb = xt + ((size_t)b * NP + n0) * CD;

  floatx4 acc[4][4] = {};
  for (int c = 0; c < CD; c += 32) {
    half8 a[4], bf[4];
#pragma unroll
    for (int i = 0; i < 4; i++)
      a[i] = *(const half8*)(w_h + (size_t)(r0 + i * 16 + col) * CD + c + quad * 8);
#pragma unroll
    for (int j = 0; j < 4; j++)
      bf[j] = *(const half8*)(xtb + (size_t)(j * 16 + col) * CD + c + quad * 8);
#pragma unroll
    for (int i = 0; i < 4; i++)
#pragma unroll
      for (int j = 0; j < 4; j++)
        acc[i][j] = __builtin_amdgcn_mfma_f32_16x16x32_f16(a[i], bf[j], acc[i][j], 0, 0, 0);
  }

  if (rb < 2) {
#pragma unroll
    for (int i = 0; i < 4; i++) {
      float bi[4];
#pragma unroll
      for (int rr = 0; rr < 4; rr++) bi[rr] = bias[r0 + i * 16 + quad * 4 + rr];
      _Float16* dst = (rb == 0 ? q_h : k_h) + (size_t)b * NP * MID;
#pragma unroll
      for (int j = 0; j < 4; j++) {
        int n = n0 + j * 16 + col;
        half4 pk;
#pragma unroll
        for (int rr = 0; rr < 4; rr++) pk[rr] = (_Float16)(acc[i][j][rr] + bi[rr]);
        *(half4*)(dst + (size_t)n * MID + i * 16 + quad * 4) = pk;
      }
    }
  } else {
    // V tile: bounce through LDS so global stores are row-contiguous b128
#pragma unroll
    for (int i = 0; i < 4; i++) {
      float bi[4];
#pragma unroll
      for (int rr = 0; rr < 4; rr++) bi[rr] = bias[r0 + i * 16 + quad * 4 + rr];
#pragma unroll
      for (int j = 0; j < 4; j++)
#pragma unroll
        for (int rr = 0; rr < 4; rr++)
          st[(i * 16 + quad * 4 + rr) * 72 + j * 16 + col] =
              (_Float16)(acc[i][j][rr] + bi[rr]);
    }
    int dbase = (rb - 2) * 64;
#pragma unroll
    for (int k = 0; k < 8; k++) {
      int u = lane + k * 64;
      int row = u >> 3, off = (u & 7) * 8;
      *(half8*)(v_h + ((size_t)b * CD + dbase + row) * NP + n0 + off) =
          *(const half8*)(st + row * 72 + off);
    }
  }
}

// ---------------------------------------------------------------------------
// Kernel 4: row max of S (log2-domain). Block = 32 q; 4 waves split the 4096
// keys 4-way; A=K loads amortized over 2 q-tiles. Grid (128, B).
// ---------------------------------------------------------------------------
__global__ __launch_bounds__(256) void rowmax(const _Float16* __restrict__ q_h,
                                              const _Float16* __restrict__ k_h,
                                              float* __restrict__ M) {
  int qb = blockIdx.x, b = blockIdx.y;
  int t = threadIdx.x, w = t >> 6, lane = t & 63;
  int col = lane & 15, quad = lane >> 4;
  int q0 = qb * 32;
  const _Float16* qp = q_h + ((size_t)b * NP + q0) * MID;
  half8 bq[2][2];
#pragma unroll
  for (int qt = 0; qt < 2; qt++)
#pragma unroll
    for (int h = 0; h < 2; h++)
      bq[qt][h] = *(const half8*)(qp + (size_t)(qt * 16 + col) * MID + h * 32 + quad * 8);
  const _Float16* kp = k_h + ((size_t)b * NP + (size_t)w * 1024) * MID;
  float m[2] = {-1e30f, -1e30f};
#pragma unroll 4
  for (int n = 0; n < 1024; n += 16) {
    half8 ak0 = *(const half8*)(kp + (size_t)(n + col) * MID + quad * 8);
    half8 ak1 = *(const half8*)(kp + (size_t)(n + col) * MID + 32 + quad * 8);
#pragma unroll
    for (int qt = 0; qt < 2; qt++) {
      floatx4 s = {};
      s = __builtin_amdgcn_mfma_f32_16x16x32_f16(ak0, bq[qt][0], s, 0, 0, 0);
      s = __builtin_amdgcn_mfma_f32_16x16x32_f16(ak1, bq[qt][1], s, 0, 0, 0);
      m[qt] = fmaxf(m[qt], fmaxf(fmaxf(s[0], s[1]), fmaxf(s[2], s[3])));
    }
  }
  __shared__ float red[4][2][16];
#pragma unroll
  for (int qt = 0; qt < 2; qt++) {
    m[qt] = fmaxf(m[qt], __shfl_xor(m[qt], 16));
    m[qt] = fmaxf(m[qt], __shfl_xor(m[qt], 32));
  }
  if (quad == 0) {
    red[w][0][col] = m[0];
    red[w][1][col] = m[1];
  }
  __syncthreads();
  if (t < 32) {
    int qt = t >> 4, c = t & 15;
    float mm = fmaxf(fmaxf(red[0][qt][c], red[1][qt][c]),
                     fmaxf(red[2][qt][c], red[3][qt][c]));
    M[(size_t)b * NP + q0 + t] = mm;
  }
}

// ---------------------------------------------------------------------------
// Kernel 5: attention + PV + epilogue, v3 — barrier-free main loop.
// Grid 1024 = b(4) x ds(4: 128 d each) x qb(64). Block = 4 waves; wave w owns
// interleaved 64-key chunks (nc = (ci*4+w)*64): computes scores for ALL 64 q
// of the block vs its keys (A=K from global/L2), exp2 -> wave-PRIVATE pbuf
// ([q][k], no barrier), PV with A=V from global/L2 into 128d x 64q acc.
// End: rotating-section LDS reduce across the 4 waves (obuf aliases pbuf:
// wave w's pbuf region == obuf d-section w, both 8704 B), then fused
// alpha/l + residual epilogue with coalesced float4 stores.
// XCD swizzle: XCD x hosts (b,ds) combos {2x, 2x+1} -> K(b)+2 V-slices ~3MB
// resident in its 4MB L2.
// ---------------------------------------------------------------------------
__global__ __launch_bounds__(256, 2) void attn_pv(
    const _Float16* __restrict__ q_h, const _Float16* __restrict__ k_h,
    const _Float16* __restrict__ v_h, const float* __restrict__ M,
    const float* __restrict__ x, const float* __restrict__ alpha_p,
    float* __restrict__ out) {
  int bid = blockIdx.x;
  int xcd = bid & 7;
  int i = bid >> 3;                  // 0..127
  int combo = xcd * 2 + (i & 1);     // 0..15
  int b = combo >> 2, ds = combo & 3;
  int qb = i >> 1;                   // 0..63
  int q0 = qb * 64, d0 = ds * 128;

  int t = threadIdx.x, w = t >> 6, lane = t & 63;
  int col = lane & 15, quad = lane >> 4;

  // 4 waves x 64 q-rows x PSTR halves = 34816 B; aliased later as
  // float obuf[128][PSTR] = 34816 B (exact).
  __shared__ _Float16 smem_h[4 * 64 * PSTR];
  __shared__ float lred[4][4][16];   // [wave][qt][col]
  __shared__ float lfin[64];

  _Float16* pb = smem_h + (size_t)w * 64 * PSTR;

  const _Float16* qp = q_h + ((size_t)b * NP + q0) * MID;
  half8 bq[4][2];
#pragma unroll
  for (int qt = 0; qt < 4; qt++)
#pragma unroll
    for (int h = 0; h < 2; h++)
      bq[qt][h] = *(const half8*)(qp + (size_t)(qt * 16 + col) * MID + h * 32 + quad * 8);
  float Mq[4];
#pragma unroll
  for (int qt = 0; qt < 4; qt++) Mq[qt] = M[(size_t)b * NP + q0 + qt * 16 + col];

  const _Float16* kp = k_h + (size_t)b * NP * MID;
  const _Float16* vp = v_h + ((size_t)b * CD + d0) * NP;

  floatx4 acc[8][4] = {};            // [dt (16 d each)][qt]
  float lp[4] = {0.f, 0.f, 0.f, 0.f};

  for (int ci = 0; ci < 16; ci++) {
    int nc = (ci * 4 + w) * 64;      // this wave's key chunk

    // scores: D[key][q] tiles; A=K straight from global (L2-resident)
#pragma unroll
    for (int kt = 0; kt < 4; kt++) {
      const _Float16* krow = kp + (size_t)(nc + kt * 16 + col) * MID;
      half8 ak0 = *(const half8*)(krow + quad * 8);
      half8 ak1 = *(const half8*)(krow + 32 + quad * 8);
#pragma unroll
      for (int qt = 0; qt < 4; qt++) {
        floatx4 s = {};
        s = __builtin_amdgcn_mfma_f32_16x16x32_f16(ak0, bq[qt][0], s, 0, 0, 0);
        s = __builtin_amdgcn_mfma_f32_16x16x32_f16(ak1, bq[qt][1], s, 0, 0, 0);
        half4 pk;
#pragma unroll
        for (int r = 0; r < 4; r++) {
          float p = exp2f(s[r] - Mq[qt]);
          lp[qt] += p;
          pk[r] = (_Float16)p;
        }
        // pbuf layout [q][k]: row q=qt*16+col, 4 contiguous keys per lane
        *(half4*)(pb + (qt * 16 + col) * PSTR + kt * 16 + quad * 4) = pk;
      }
    }

    // PV: O^T, A=V[d][n] (global/L2), B=P^T from wave-private pbuf
#pragma unroll
    for (int f = 0; f < 2; f++) {
      half8 bp[4];
#pragma unroll
      for (int qt = 0; qt < 4; qt++)
        bp[qt] = *(const half8*)(pb + (qt * 16 + col) * PSTR + f * 32 + quad * 8);
#pragma unroll
      for (int dt = 0; dt < 8; dt++) {
        half8 av = *(const half8*)(vp + (size_t)(dt * 16 + col) * NP + nc + f * 32 + quad * 8);
#pragma unroll
        for (int qt = 0; qt < 4; qt++)
          acc[dt][qt] = __builtin_amdgcn_mfma_f32_16x16x32_f16(av, bp[qt], acc[dt][qt], 0, 0, 0);
      }
    }
  }

  // l partials: reduce across quads (keys) within wave
#pragma unroll
  for (int qt = 0; qt < 4; qt++) {
    lp[qt] += __shfl_xor(lp[qt], 16);
    lp[qt] += __shfl_xor(lp[qt], 32);
    if (quad == 0) lred[w][qt][col] = lp[qt];
  }

  // Cross-wave O reduction: rotating d-sections. Section s rows [32s,32s+32)
  // occupy obuf floats [2176s, 2176(s+1)) == wave s's pbuf bytes (safe @p=0).
  float* obuf = (float*)smem_h;
#pragma unroll
  for (int p = 0; p < 4; p++) {
    if (p) __syncthreads();
    int s = (w + p) & 3;
#pragma unroll
    for (int dd = 0; dd < 2; dd++) {
      int dt = s * 2 + dd;
#pragma unroll
      for (int qt = 0; qt < 4; qt++)
#pragma unroll
        for (int r = 0; r < 4; r++) {
          float* ap = obuf + (dt * 16 + quad * 4 + r) * PSTR + qt * 16 + col;
          if (p == 0) *ap = acc[dt][qt][r];
          else        *ap += acc[dt][qt][r];
        }
    }
  }
  __syncthreads();
  if (t < 64) {
    float l = lred[0][t >> 4][t & 15] + lred[1][t >> 4][t & 15] +
              lred[2][t >> 4][t & 15] + lred[3][t >> 4][t & 15];
    lfin[t] = alpha_p[0] / l;
  }
  __syncthreads();

  // epilogue: coalesced float4, fused alpha/l scale + residual
  const float* xp = x + (size_t)b * CD * NP;
  float* op = out + (size_t)b * CD * NP;
#pragma unroll
  for (int i2 = 0; i2 < 8; i2++) {
    int u = t + i2 * 256;
    int row = u >> 4;                // 0..127
    int c4 = (u & 15) * 4;
    floatx4 o = *(const floatx4*)(obuf + row * PSTR + c4);
    floatx4 lv = *(const floatx4*)(lfin + c4);
    size_t g = (size_t)(d0 + row) * NP + q0 + c4;
    floatx4 xv = *(const floatx4*)(xp + g);
    floatx4 res = o * lv + xv;
    *(floatx4*)(op + g) = res;
  }
}

// ---------------------------------------------------------------------------
extern "C" void kernel_launch(void* const* d_in, const int* in_sizes, int n_in,
                              void* d_out, int out_size, void* d_ws, size_t ws_size,
                              hipStream_t stream) {
  const float* x     = (const float*)d_in[0];
  const float* wq    = (const float*)d_in[1];
  const float* bq    = (const float*)d_in[2];
  const float* wk    = (const float*)d_in[3];
  const float* bk    = (const float*)d_in[4];
  const float* wv    = (const float*)d_in[5];
  const float* bv    = (const float*)d_in[6];
  const float* alpha = (const float*)d_in[7];
  float* out = (float*)d_out;

  char* ws = (char*)d_ws;
  _Float16* w_h  = (_Float16*)(ws);                    // 640*512*2   = 655360
  float*    bias = (float*)(ws + 655360);              // 640*4       = 2560
  float*    Mbuf = (float*)(ws + 657920);              // 4*4096*4    = 65536
  _Float16* xt   = (_Float16*)(ws + 723456);           // 4*4096*512*2= 16777216
  _Float16* q_h  = (_Float16*)(ws + 17500672);         // 4*4096*64*2 = 2097152
  _Float16* k_h  = (_Float16*)(ws + 19597824);         // 4*4096*64*2 = 2097152
  _Float16* v_h  = (_Float16*)(ws + 21694976);         // 4*512*4096*2= 16777216

  prep_w<<<1280, 256, 0, stream>>>(wq, wk, wv, bq, bk, bv, w_h, bias);
  transpose_x<<<dim3(64, 8, BB), 256, 0, stream>>>(x, xt);
  proj_qkv<<<dim3(10, 64, BB), 64, 0, stream>>>(w_h, bias, xt, q_h, k_h, v_h);
  rowmax<<<dim3(128, BB), 256, 0, stream>>>(q_h, k_h, Mbuf);
  attn_pv<<<1024, 256, 0, stream>>>(q_h, k_h, v_h, Mbuf, x, alpha, out);
}

// Round 4
// 309.265 us; speedup vs baseline: 1.4923x; 1.4923x over previous
//
#include <hip/hip_runtime.h>

// Problem constants (fixed by reference: B=4, C=512, H=W=64, MID=64)
#define BB 4
#define CD 512
#define NP 4096
#define MID 64
#define PSTR 88   // pbuf row stride in halves: 176B rows, 16B-aligned, ~2-way banks

typedef _Float16 half8 __attribute__((ext_vector_type(8)));
typedef _Float16 half4 __attribute__((ext_vector_type(4)));
typedef float floatx4 __attribute__((ext_vector_type(4)));

#define LOG2E 1.4426950408889634f

// ---------------------------------------------------------------------------
// Kernel 1: pack wq|wk|wv -> fp16 [640][512], concat biases (fp32 [640]).
// log2(e) folded into wq/bq so softmax uses raw v_exp_f32 (exp2).
// ---------------------------------------------------------------------------
__global__ __launch_bounds__(256) void prep_w(
    const float* __restrict__ wq, const float* __restrict__ wk,
    const float* __restrict__ wv, const float* __restrict__ bq,
    const float* __restrict__ bk, const float* __restrict__ bv,
    _Float16* __restrict__ w_h, float* __restrict__ bias) {
  int idx = blockIdx.x * 256 + threadIdx.x;
  for (int i = idx; i < 640 * 512; i += gridDim.x * 256) {
    int r = i >> 9, c = i & 511;
    float v = (r < 64) ? wq[(r << 9) + c] * LOG2E
            : (r < 128) ? wk[((r - 64) << 9) + c]
                        : wv[((r - 128) << 9) + c];
    w_h[i] = (_Float16)v;
  }
  if (idx < 640) {
    float v = (idx < 64) ? bq[idx] * LOG2E
            : (idx < 128) ? bk[idx - 64]
                          : bv[idx - 128];
    bias[idx] = v;
  }
}

// ---------------------------------------------------------------------------
// Kernel 2: transpose x [b][c][n] fp32 -> xt [b][n][c] fp16 (64x64 LDS tiles)
// ---------------------------------------------------------------------------
__global__ __launch_bounds__(256) void transpose_x(const float* __restrict__ x,
                                                   _Float16* __restrict__ xt) {
  __shared__ float tile[64][65];
  int b = blockIdx.z, c0 = blockIdx.y * 64, n0 = blockIdx.x * 64;
  int t = threadIdx.x;
  const float* xb = x + (size_t)b * CD * NP;
#pragma unroll
  for (int k = 0; k < 16; k++) {
    int cl = k * 4 + (t >> 6);
    int nl = t & 63;
    tile[cl][nl] = xb[(size_t)(c0 + cl) * NP + n0 + nl];
  }
  __syncthreads();
  _Float16* xtb = xt + ((size_t)b * NP + n0) * CD + c0;
#pragma unroll
  for (int k = 0; k < 2; k++) {
    int nl = k * 32 + (t >> 3);
    int cl = (t & 7) * 8;
    half8 pk;
#pragma unroll
    for (int i = 0; i < 8; i++) pk[i] = (_Float16)tile[cl + i][nl];
    *(half8*)(xtb + (size_t)nl * CD + cl) = pk;
  }
}

// ---------------------------------------------------------------------------
// Kernel 3: fused QKV projection, v2. Block = 4 waves, grid (2,64,4):
// rbh picks 320 of the 640 W-rows; 64-position tile staged once in LDS
// (XOR-swizzled 16B units -> conflict-free b128 reads) and shared by all
// waves; wave w computes 80 rows (5 row-tiles x 4 n-tiles, acc=80 VGPR).
// ---------------------------------------------------------------------------
__global__ __launch_bounds__(256, 2) void proj_qkv(
    const _Float16* __restrict__ w_h, const float* __restrict__ bias,
    const _Float16* __restrict__ xt, _Float16* __restrict__ q_h,
    _Float16* __restrict__ k_h, _Float16* __restrict__ v_h) {
  __shared__ _Float16 xls[64 * 512];   // 64 KB, XOR-swizzled 16B units
  int t = threadIdx.x, w = t >> 6, lane = t & 63;
  int col = lane & 15, quad = lane >> 4;
  int rbh = blockIdx.x, nb = blockIdx.y, b = blockIdx.z;
  int n0 = nb * 64;
  const _Float16* xtb = xt + ((size_t)b * NP + n0) * CD;

  // stage xt tile: 16 rounds x 256 threads x 16B; unit u stored at u^(row&7)
#pragma unroll
  for (int j = 0; j < 16; j++) {
    int u = t + j * 256;
    int row = u >> 6, un = u & 63;
    *(half8*)(xls + row * 512 + ((un ^ (row & 7)) << 3)) =
        *(const half8*)(xtb + (size_t)row * CD + un * 8);
  }
  __syncthreads();

  int rw = rbh * 320 + w * 80;        // this wave's first W-row
  floatx4 acc[5][4] = {};
  for (int c = 0; c < CD; c += 32) {
    int cu = c >> 3;                  // base 16B-unit index (multiple of 4)
    half8 a[5], bf[4];
#pragma unroll
    for (int i = 0; i < 5; i++)
      a[i] = *(const half8*)(w_h + (size_t)(rw + i * 16 + col) * CD + c + quad * 8);
#pragma unroll
    for (int j = 0; j < 4; j++) {
      int row = j * 16 + col;
      bf[j] = *(const half8*)(xls + row * 512 + (((cu + quad) ^ (row & 7)) << 3));
    }
#pragma unroll
    for (int i = 0; i < 5; i++)
#pragma unroll
      for (int j = 0; j < 4; j++)
        acc[i][j] = __builtin_amdgcn_mfma_f32_16x16x32_f16(a[i], bf[j], acc[i][j], 0, 0, 0);
  }

#pragma unroll
  for (int i = 0; i < 5; i++) {
    int r0 = rw + i * 16;             // wave-uniform tile base (mult of 16)
    float bi[4];
#pragma unroll
    for (int rr = 0; rr < 4; rr++) bi[rr] = bias[r0 + quad * 4 + rr];
    if (r0 < 128) {
      // q (r0<64) or k: store [n][m] packed half4
      _Float16* dst = (r0 < 64 ? q_h + (size_t)b * NP * MID + r0
                               : k_h + (size_t)b * NP * MID + (r0 - 64));
#pragma unroll
      for (int j = 0; j < 4; j++) {
        int n = n0 + j * 16 + col;
        half4 pk;
#pragma unroll
        for (int rr = 0; rr < 4; rr++) pk[rr] = (_Float16)(acc[i][j][rr] + bi[rr]);
        *(half4*)(dst + (size_t)n * MID + quad * 4) = pk;
      }
    } else {
      int dbase = r0 - 128 + quad * 4;
#pragma unroll
      for (int j = 0; j < 4; j++) {
        int n = n0 + j * 16 + col;
#pragma unroll
        for (int rr = 0; rr < 4; rr++)
          v_h[((size_t)b * CD + dbase + rr) * NP + n] =
              (_Float16)(acc[i][j][rr] + bi[rr]);
      }
    }
  }
}

// ---------------------------------------------------------------------------
// Kernel 4: row max of S (log2-domain). Block = 32 q; 4 waves split the 4096
// keys 4-way; A=K loads amortized over 2 q-tiles. Grid (128, B).
// ---------------------------------------------------------------------------
__global__ __launch_bounds__(256) void rowmax(const _Float16* __restrict__ q_h,
                                              const _Float16* __restrict__ k_h,
                                              float* __restrict__ M) {
  int qb = blockIdx.x, b = blockIdx.y;
  int t = threadIdx.x, w = t >> 6, lane = t & 63;
  int col = lane & 15, quad = lane >> 4;
  int q0 = qb * 32;
  const _Float16* qp = q_h + ((size_t)b * NP + q0) * MID;
  half8 bq[2][2];
#pragma unroll
  for (int qt = 0; qt < 2; qt++)
#pragma unroll
    for (int h = 0; h < 2; h++)
      bq[qt][h] = *(const half8*)(qp + (size_t)(qt * 16 + col) * MID + h * 32 + quad * 8);
  const _Float16* kp = k_h + ((size_t)b * NP + (size_t)w * 1024) * MID;
  float m[2] = {-1e30f, -1e30f};
#pragma unroll 4
  for (int n = 0; n < 1024; n += 16) {
    half8 ak0 = *(const half8*)(kp + (size_t)(n + col) * MID + quad * 8);
    half8 ak1 = *(const half8*)(kp + (size_t)(n + col) * MID + 32 + quad * 8);
#pragma unroll
    for (int qt = 0; qt < 2; qt++) {
      floatx4 s = {};
      s = __builtin_amdgcn_mfma_f32_16x16x32_f16(ak0, bq[qt][0], s, 0, 0, 0);
      s = __builtin_amdgcn_mfma_f32_16x16x32_f16(ak1, bq[qt][1], s, 0, 0, 0);
      m[qt] = fmaxf(m[qt], fmaxf(fmaxf(s[0], s[1]), fmaxf(s[2], s[3])));
    }
  }
  __shared__ float red[4][2][16];
#pragma unroll
  for (int qt = 0; qt < 2; qt++) {
    m[qt] = fmaxf(m[qt], __shfl_xor(m[qt], 16));
    m[qt] = fmaxf(m[qt], __shfl_xor(m[qt], 32));
  }
  if (quad == 0) {
    red[w][0][col] = m[0];
    red[w][1][col] = m[1];
  }
  __syncthreads();
  if (t < 32) {
    int qt = t >> 4, c = t & 15;
    float mm = fmaxf(fmaxf(red[0][qt][c], red[1][qt][c]),
                     fmaxf(red[2][qt][c], red[3][qt][c]));
    M[(size_t)b * NP + q0 + t] = mm;
  }
}

// ---------------------------------------------------------------------------
// Kernel 5: attention + PV + epilogue, v4.
// Grid 512 = b(4) x ds(2: 256 d) x qb(64); block = 4 waves = 64q x 256d.
// Per 64-key chunk: wave w scores ITS 16 keys vs all 64 q (K-frag read once
// per block), P -> double-buffered shared pbuf; ONE barrier; each wave PV
// for its private 64d x 64q over the full chunk (acc[4][4], all indices
// compile-time -> no spill). V-frags prefetched into regs before the barrier.
// No cross-wave O reduction needed; l reduced once at the end.
// XCD swizzle: XCD x hosts combo x -> K(b)+V-half ~2.5MB in its 4MB L2.
// ---------------------------------------------------------------------------
__global__ __launch_bounds__(256, 2) void attn_pv(
    const _Float16* __restrict__ q_h, const _Float16* __restrict__ k_h,
    const _Float16* __restrict__ v_h, const float* __restrict__ M,
    const float* __restrict__ x, const float* __restrict__ alpha_p,
    float* __restrict__ out) {
  int bid = blockIdx.x;
  int combo = bid & 7;               // -> XCD via round-robin dispatch
  int b = combo >> 1, ds = combo & 1;
  int qb = bid >> 3;                 // 0..63
  int q0 = qb * 64, d0 = ds * 256;

  int t = threadIdx.x, w = t >> 6, lane = t & 63;
  int col = lane & 15, quad = lane >> 4;

  __shared__ _Float16 pbuf[2][64 * PSTR];   // 22.5 KB double-buffered P
  __shared__ float lred[4][4][16];
  __shared__ float lfin[64];

  const _Float16* qp = q_h + ((size_t)b * NP + q0) * MID;
  half8 bq[4][2];
#pragma unroll
  for (int qt = 0; qt < 4; qt++)
#pragma unroll
    for (int h = 0; h < 2; h++)
      bq[qt][h] = *(const half8*)(qp + (size_t)(qt * 16 + col) * MID + h * 32 + quad * 8);
  float Mq[4];
#pragma unroll
  for (int qt = 0; qt < 4; qt++) Mq[qt] = M[(size_t)b * NP + q0 + qt * 16 + col];

  const _Float16* kp = k_h + (size_t)b * NP * MID;
  const _Float16* vp = v_h + ((size_t)(b * CD + d0) + w * 64) * NP;

  floatx4 acc[4][4] = {};            // [dt][qt] = 64 VGPRs, static indices
  float lp[4] = {0.f, 0.f, 0.f, 0.f};

  for (int ci = 0; ci < 64; ci++) {
    int nc = ci * 64;
    _Float16* pb = pbuf[ci & 1];

    // ---- score phase: this wave's 16 keys vs all 64 q ----
    const _Float16* kr = kp + (size_t)(nc + w * 16 + col) * MID;
    half8 ak0 = *(const half8*)(kr + quad * 8);
    half8 ak1 = *(const half8*)(kr + 32 + quad * 8);

    // prefetch this wave's V frags for the chunk (consumed after barrier)
    half8 av[2][4];
#pragma unroll
    for (int f = 0; f < 2; f++)
#pragma unroll
      for (int dt = 0; dt < 4; dt++)
        av[f][dt] = *(const half8*)(vp + (size_t)(dt * 16 + col) * NP + nc + f * 32 + quad * 8);

#pragma unroll
    for (int qt = 0; qt < 4; qt++) {
      floatx4 s = {};
      s = __builtin_amdgcn_mfma_f32_16x16x32_f16(ak0, bq[qt][0], s, 0, 0, 0);
      s = __builtin_amdgcn_mfma_f32_16x16x32_f16(ak1, bq[qt][1], s, 0, 0, 0);
      half4 pk;
#pragma unroll
      for (int r = 0; r < 4; r++) {
        float p = exp2f(s[r] - Mq[qt]);
        lp[qt] += p;
        pk[r] = (_Float16)p;
      }
      // row = q-local, col = key-local (this wave's 16-key section)
      *(half4*)(pb + (qt * 16 + col) * PSTR + w * 16 + quad * 4) = pk;
    }
    __syncthreads();

    // ---- PV phase: private 64d x 64q over the full 64-key chunk ----
#pragma unroll
    for (int f = 0; f < 2; f++) {
      half8 bp[4];
#pragma unroll
      for (int qt = 0; qt < 4; qt++)
        bp[qt] = *(const half8*)(pb + (qt * 16 + col) * PSTR + f * 32 + quad * 8);
#pragma unroll
      for (int dt = 0; dt < 4; dt++)
#pragma unroll
        for (int qt = 0; qt < 4; qt++)
          acc[dt][qt] = __builtin_amdgcn_mfma_f32_16x16x32_f16(av[f][dt], bp[qt], acc[dt][qt], 0, 0, 0);
    }
  }

  // l: lane's partial covers its quad's 4 keys of this wave's sections
#pragma unroll
  for (int qt = 0; qt < 4; qt++) {
    lp[qt] += __shfl_xor(lp[qt], 16);
    lp[qt] += __shfl_xor(lp[qt], 32);
    if (quad == 0) lred[w][qt][col] = lp[qt];
  }
  __syncthreads();
  if (t < 64) {
    int qt = t >> 4, c = t & 15;
    float l = lred[0][qt][c] + lred[1][qt][c] + lred[2][qt][c] + lred[3][qt][c];
    lfin[t] = alpha_p[0] / l;
  }
  __syncthreads();

  // epilogue: fused alpha/l scale + residual; 64B-segment coalesced stores
  const float* xp = x + ((size_t)(b * CD + d0) + w * 64) * NP;
  float* op = out + ((size_t)(b * CD + d0) + w * 64) * NP;
#pragma unroll
  for (int dt = 0; dt < 4; dt++)
#pragma unroll
    for (int qt = 0; qt < 4; qt++) {
      float linv = lfin[qt * 16 + col];
#pragma unroll
      for (int r = 0; r < 4; r++) {
        size_t o = (size_t)(dt * 16 + quad * 4 + r) * NP + q0 + qt * 16 + col;
        op[o] = acc[dt][qt][r] * linv + xp[o];
      }
    }
}

// ---------------------------------------------------------------------------
extern "C" void kernel_launch(void* const* d_in, const int* in_sizes, int n_in,
                              void* d_out, int out_size, void* d_ws, size_t ws_size,
                              hipStream_t stream) {
  const float* x     = (const float*)d_in[0];
  const float* wq    = (const float*)d_in[1];
  const float* bq    = (const float*)d_in[2];
  const float* wk    = (const float*)d_in[3];
  const float* bk    = (const float*)d_in[4];
  const float* wv    = (const float*)d_in[5];
  const float* bv    = (const float*)d_in[6];
  const float* alpha = (const float*)d_in[7];
  float* out = (float*)d_out;

  char* ws = (char*)d_ws;
  _Float16* w_h  = (_Float16*)(ws);                    // 640*512*2   = 655360
  float*    bias = (float*)(ws + 655360);              // 640*4       = 2560
  float*    Mbuf = (float*)(ws + 657920);              // 4*4096*4    = 65536
  _Float16* xt   = (_Float16*)(ws + 723456);           // 4*4096*512*2= 16777216
  _Float16* q_h  = (_Float16*)(ws + 17500672);         // 4*4096*64*2 = 2097152
  _Float16* k_h  = (_Float16*)(ws + 19597824);         // 4*4096*64*2 = 2097152
  _Float16* v_h  = (_Float16*)(ws + 21694976);         // 4*512*4096*2= 16777216

  prep_w<<<1280, 256, 0, stream>>>(wq, wk, wv, bq, bk, bv, w_h, bias);
  transpose_x<<<dim3(64, 8, BB), 256, 0, stream>>>(x, xt);
  proj_qkv<<<dim3(2, 64, BB), 256, 0, stream>>>(w_h, bias, xt, q_h, k_h, v_h);
  rowmax<<<dim3(128, BB), 256, 0, stream>>>(q_h, k_h, Mbuf);
  attn_pv<<<512, 256, 0, stream>>>(q_h, k_h, v_h, Mbuf, x, alpha, out);
}